// Round 11
// baseline (115.458 us; speedup 1.0000x reference)
//
#include <hip/hip_runtime.h>

typedef __bf16 bf16;
typedef __bf16 bf16x8 __attribute__((ext_vector_type(8)));
typedef float f32x4 __attribute__((ext_vector_type(4)));

#define S_LEN 2048
#define EMBD 2048
#define HD 128

__device__ inline void gload16(const void* g, void* l) {
  __builtin_amdgcn_global_load_lds(
      (const __attribute__((address_space(1))) unsigned int*)g,
      (__attribute__((address_space(3))) unsigned int*)l, 16, 0, 0);
}

// ---------------------------------------------------------------------------
// K0: Wt[mat][n][k] = bf16( W[ (k&~63) | ((k&63) ^ ((n&7)<<3)) ][n] )
// Coalesced via LDS transpose: block = (mat, n-tile of 64, k-tile of 64).
// ---------------------------------------------------------------------------
__global__ __launch_bounds__(256) void k_prep(const float* __restrict__ Wq,
                                              const float* __restrict__ Wk,
                                              const float* __restrict__ Wv,
                                              bf16* __restrict__ wt) {
  __shared__ bf16 wls[64 * 72];  // [k][n] padded

  const int t = threadIdx.x;
  const int bid = blockIdx.x;           // 3 * 2 * 32 = 192 blocks
  const int mat = bid >> 6;
  const int nt = bid & 1;
  const int kt = (bid & 63) >> 1;
  const int k0 = kt * 64, n0 = nt * 64;
  const float* W = (mat == 0) ? Wq : ((mat == 1) ? Wk : Wv);

#pragma unroll
  for (int i = 0; i < 4; ++i) {
    int e = i * 256 + t;          // 0..1023
    int r = e >> 4, c4 = e & 15;  // row k, 4-col group
    float4 v = *(const float4*)(W + (size_t)(k0 + r) * HD + n0 + c4 * 4);
    union { bf16 h[4]; uint2 u; } p;
    p.h[0] = (bf16)v.x; p.h[1] = (bf16)v.y;
    p.h[2] = (bf16)v.z; p.h[3] = (bf16)v.w;
    *(uint2*)&wls[r * 72 + c4 * 4] = p.u;
  }
  __syncthreads();
#pragma unroll
  for (int i = 0; i < 2; ++i) {
    int slot = i * 256 + t;  // 0..511: n_loc = slot>>3, kq = slot&7
    int n_loc = slot >> 3, kq = slot & 7;
    int n = n0 + n_loc;
    int kbase = (kq * 8) ^ ((n & 7) << 3);
    union { bf16 h[8]; uint4 u; } p;
#pragma unroll
    for (int j = 0; j < 8; ++j) p.h[j] = wls[(kbase + j) * 72 + n_loc];
    *(uint4*)&wt[(size_t)(mat * HD + n) * EMBD + k0 + kq * 8] = p.u;
  }
}

// ---------------------------------------------------------------------------
// K1: fused QKV GEMM + bias + RoPE. BM=64, BN=128, BK=128 (16 fat K-steps);
// by = 0:Q,1:K,2:V. 256 thr / 4 waves (2m x 2n), wave-tile 32x64 with
// RoPE-pair col interleave (R5's best-measured economics: 32 MFMA : 24
// ds_read per wave-step). SINGLE-buffered LDS (2 barriers/step): xs 17.4 KB
// + wts 32.8 KB = 50.2 KB -> 3 blocks/CU, grid 768 = exactly 3/CU.
// x(k+1) register-prefetched above the MFMA phase (latency hidden by MFMA);
// w gload exposure after barrier1 covered by the other 2 resident blocks.
// ---------------------------------------------------------------------------
__global__ __launch_bounds__(256) void k_qkv(
    const float* __restrict__ x, const bf16* __restrict__ wt,
    const float* __restrict__ bq, const float* __restrict__ bk,
    const float* __restrict__ bv, bf16* __restrict__ Qw, bf16* __restrict__ Kw,
    bf16* __restrict__ Vtw) {
  __shared__ __align__(16) bf16 xs[64 * 136];   // 17.4 KB, pad 8
  __shared__ __align__(16) bf16 wts[128 * 128]; // 32.8 KB, swizzle pre-baked

  const int tid = threadIdx.x;
  const int lane = tid & 63;
  const int wave = tid >> 6;
  const int wm = wave >> 1;  // 0..1: 32-row half
  const int wn = wave & 1;   // 0..1: 32+32 col slice (pairs c, c+64 in-wave)
  const int l15 = lane & 15;
  const int lh = lane >> 4;  // 0..3

  // bid = xcd + 8*idx: by = idx%3, mt = xcd*32 + idx/3 (3 by-blocks of an
  // m-tile land on one XCD -> x L2/L3 reuse).
  const int bid = blockIdx.x;
  const int xcd = bid & 7;
  const int idx = bid >> 3;
  const int by = idx % 3;  // 0:Q 1:K 2:V
  const int mt = xcd * 32 + idx / 3;
  const int row0 = mt * 64;

  f32x4 acc[2][4];  // [mf][f]; col(f) = (f&1)*16 + (f>>1)*64 + wn*32
#pragma unroll
  for (int mf = 0; mf < 2; ++mf)
#pragma unroll
    for (int f = 0; f < 4; ++f) acc[mf][f] = {};

  // x staging: 64x128 f32 = 8 float4/thread, coalesced
  int xr_[8], xk_[8];
  const float* xp_[8];
#pragma unroll
  for (int i = 0; i < 8; ++i) {
    int e = (i * 256 + tid) * 4;
    xr_[i] = e >> 7;
    xk_[i] = e & 127;
    xp_[i] = x + (size_t)(row0 + xr_[i]) * EMBD + xk_[i];
  }
  // B staging: 128x128 bf16 = 8 gload16/thread
  const bf16* wp_[8];
  int we_[8];
#pragma unroll
  for (int i = 0; i < 8; ++i) {
    int e = (i * 256 + tid) * 8;
    int np = e >> 7, k = e & 127;
    wp_[i] = wt + (size_t)(by * 128 + np) * EMBD + k;
    we_[i] = e;
  }

  auto xload = [&](int ks, float4* xr) {
#pragma unroll
    for (int i = 0; i < 8; ++i) xr[i] = *(const float4*)(xp_[i] + ks * 128);
  };
  auto xwrite = [&](const float4* xr) {
#pragma unroll
    for (int i = 0; i < 8; ++i) {
      union { bf16 h[4]; uint2 u; } p;
      p.h[0] = (bf16)xr[i].x; p.h[1] = (bf16)xr[i].y;
      p.h[2] = (bf16)xr[i].z; p.h[3] = (bf16)xr[i].w;
      *(uint2*)&xs[xr_[i] * 136 + xk_[i]] = p.u;
    }
  };
  auto wstage = [&](int ks) {
#pragma unroll
    for (int i = 0; i < 8; ++i) gload16(wp_[i] + ks * 128, &wts[we_[i]]);
  };

  // ---- prologue: tile 0 ----
  {
    float4 xr[8];
    xload(0, xr);
    wstage(0);
    xwrite(xr);
  }
  __syncthreads();

  float4 xnext[8];
  for (int ks = 0; ks < 16; ++ks) {
    if (ks + 1 < 16) xload(ks + 1, xnext);  // prefetch above MFMA

    __builtin_amdgcn_s_setprio(1);
#pragma unroll
    for (int kk = 0; kk < 4; ++kk) {
      bf16x8 a[2];
#pragma unroll
      for (int mf = 0; mf < 2; ++mf)
        a[mf] = *(const bf16x8*)&xs[(wm * 32 + mf * 16 + l15) * 136 + kk * 32 + lh * 8];
#pragma unroll
      for (int f = 0; f < 4; ++f) {
        int col = (f & 1) * 16 + (f >> 1) * 64 + wn * 32 + l15;
        int klin = (kk * 32 + lh * 8) ^ ((col & 7) << 3);
        bf16x8 b = *(const bf16x8*)&wts[col * 128 + klin];
#pragma unroll
        for (int mf = 0; mf < 2; ++mf)
          acc[mf][f] =
              __builtin_amdgcn_mfma_f32_16x16x32_bf16(a[mf], b, acc[mf][f], 0, 0, 0);
      }
    }
    __builtin_amdgcn_s_setprio(0);

    __syncthreads();  // barrier1: all waves done reading xs/wts
    if (ks + 1 < 16) {
      wstage(ks + 1);   // single-buffer refill (safe after barrier1)
      xwrite(xnext);    // regs loaded pre-MFMA -> latency already hidden
      __syncthreads();  // barrier2: staging visible (drains gloads)
    }
  }

  const int bb = row0 >> 11;
  const int s0 = row0 & (S_LEN - 1);

  if (by < 2) {  // Q or K: bias + RoPE, direct store
    const float* bias = (by == 0) ? bq : bk;
#pragma unroll
    for (int fp = 0; fp < 2; ++fp) {
      const int colA = wn * 32 + fp * 16 + l15;  // 0..63
      const int colB = colA + 64;
      float biasA = bias[colA], biasB = bias[colB];
      float invf = exp2f((float)colA * -0.20762050593046014f);  // -log2(1e4)/64
#pragma unroll
      for (int mf = 0; mf < 2; ++mf) {
#pragma unroll
        for (int r = 0; r < 4; ++r) {
          int s = s0 + wm * 32 + mf * 16 + lh * 4 + r;
          float xa_ = acc[mf][fp][r] + biasA;
          float xb_ = acc[mf][fp + 2][r] + biasB;
          float sn, cs;
          sincosf((float)s * invf, &sn, &cs);
          float oa = xa_ * cs - xb_ * sn;
          float ob = xa_ * sn + xb_ * cs;
          if (by == 0) {
            Qw[(size_t)(bb * S_LEN + s) * HD + colA] = (bf16)oa;
            Qw[(size_t)(bb * S_LEN + s) * HD + colB] = (bf16)ob;
          } else {
            int sw = (s & 7) << 3;
            Kw[(size_t)(bb * S_LEN + s) * HD + (colA ^ sw)] = (bf16)oa;
            Kw[(size_t)(bb * S_LEN + s) * HD + (colB ^ sw)] = (bf16)ob;
          }
        }
      }
    }
  } else {  // V: bias, transpose 128x64 through LDS (wts arena), swz store
    __syncthreads();  // all waves done with wts before scratch reuse
    bf16* vstage = &wts[0];  // needs 128*72 = 9216 <= 16384 elems
#pragma unroll
    for (int f = 0; f < 4; ++f) {
      int dv = (f & 1) * 16 + (f >> 1) * 64 + wn * 32 + l15;
      float biasV = bv[dv];
#pragma unroll
      for (int mf = 0; mf < 2; ++mf)
#pragma unroll
        for (int r = 0; r < 4; ++r) {
          int mrow = wm * 32 + mf * 16 + lh * 4 + r;
          vstage[dv * 72 + mrow] = (bf16)(acc[mf][f][r] + biasV);
        }
    }
    __syncthreads();
#pragma unroll
    for (int i = 0; i < 4; ++i) {
      int c = i * 256 + tid;  // 0..1023: dv = c>>3, kq = c&7
      int dv = c >> 3, kq = c & 7;
      uint4 v = *(const uint4*)&vstage[dv * 72 + kq * 8];
      int slot = (kq * 8) ^ ((dv & 7) << 3);
      *(uint4*)&Vtw[((size_t)(bb * HD + dv) << 11) + s0 + slot] = v;
    }
  }
}

// ---------------------------------------------------------------------------
// K2: causal flash attention. 512 thr = 2 groups x 4 waves; groups split the
// KV range (even/odd tiles) and merge (m,l,o) via LDS at the end.
// ---------------------------------------------------------------------------
__global__ __launch_bounds__(512) void k_attn(
    const bf16* __restrict__ Qw, const bf16* __restrict__ Kw,
    const bf16* __restrict__ Vtw, float* __restrict__ out) {
  __shared__ __align__(16) char arena[131072];       // 128 KB: K/V dbuf x 2 grp
  __shared__ __align__(16) bf16 pld[8 * 16 * 72];    // 18.4 KB
  __shared__ float mls[64], lls[64];

  bf16(*kls)[64 * 128] = (bf16(*)[64 * 128])arena;             // [grp*2+buf]
  bf16(*vls)[128 * 64] = (bf16(*)[128 * 64])(arena + 65536);   // [grp*2+buf]
  float* oml = (float*)arena;  // merge area: 64 x 128 f32 (aliases kls[0..1])

  const int tid = threadIdx.x;
  const int lane = tid & 63;
  const int wave = tid >> 6;
  const int grp = wave >> 2;
  const int w4 = wave & 3;
  const int l15 = lane & 15;
  const int lh = lane >> 4;
  const int t256 = tid & 255;

  const int bid = blockIdx.x;
  const int batch = bid & 7;  // batch == XCD (round-robin) -> KV L2 locality
  const int qt = 31 - (bid >> 3);
  const int qbase = qt * 64;
  const int nt = qt + 1;
  const int mysteps = (nt - grp + 1) >> 1;  // grp0: ceil(nt/2), grp1: floor
  const int maxst = (nt + 1) >> 1;

  const bf16* kbat = Kw + (size_t)(batch * S_LEN) * HD;
  const bf16* vbat = Vtw + ((size_t)(batch * HD) << 11);

  auto stage = [&](int t, int buf) {
    bf16* kdst = kls[grp * 2 + buf];
    bf16* vdst = vls[grp * 2 + buf];
    const bf16* kbase = kbat + (size_t)(t * 64) * HD;
#pragma unroll
    for (int i = 0; i < 4; ++i) {
      int c = i * 256 + t256;
      gload16(kbase + c * 8, kdst + c * 8);
    }
    const bf16* vbase = vbat + t * 64;
#pragma unroll
    for (int i = 0; i < 4; ++i) {
      int c = i * 256 + t256;
      int dv = c >> 3, kq = (c & 7) * 8;
      gload16(vbase + ((size_t)dv << 11) + kq, vdst + c * 8);
    }
  };

  bf16x8 qa[4];
  {
    const bf16* qptr = Qw + (size_t)(batch * S_LEN + qbase + w4 * 16 + l15) * HD;
#pragma unroll
    for (int kk = 0; kk < 4; ++kk) qa[kk] = *(const bf16x8*)(qptr + kk * 32 + lh * 8);
  }

  f32x4 o[8];
#pragma unroll
  for (int i = 0; i < 8; ++i) o[i] = {};
  float m[4], lsum[4];
#pragma unroll
  for (int r = 0; r < 4; ++r) { m[r] = -__builtin_inff(); lsum[r] = 0.f; }

  const float scale = 0.08838834764831845f;  // 1/sqrt(128)

  if (mysteps > 0) stage(grp, 0);
  __syncthreads();

  for (int i = 0; i < maxst; ++i) {
    if (i + 1 < mysteps) stage(2 * (i + 1) + grp, (i + 1) & 1);
    if (i < mysteps) {
      const int t = 2 * i + grp;
      const int buf = grp * 2 + (i & 1);
      const int kv0 = t * 64;

      f32x4 sc[4];
#pragma unroll
      for (int nf = 0; nf < 4; ++nf) sc[nf] = {};
      __builtin_amdgcn_s_setprio(1);
#pragma unroll
      for (int kk = 0; kk < 4; ++kk) {
#pragma unroll
        for (int nf = 0; nf < 4; ++nf) {
          int row = nf * 16 + l15;
          int dlin = (kk * 32 + lh * 8) ^ ((row & 7) << 3);
          bf16x8 kb = *(const bf16x8*)&kls[buf][row * 128 + dlin];
          sc[nf] = __builtin_amdgcn_mfma_f32_16x16x32_bf16(qa[kk], kb, sc[nf], 0, 0, 0);
        }
      }
      __builtin_amdgcn_s_setprio(0);

      const bool diag = (t == qt);
      const int qg0 = qbase + w4 * 16 + lh * 4;
#pragma unroll
      for (int nf = 0; nf < 4; ++nf) {
        int kvg = kv0 + nf * 16 + l15;
#pragma unroll
        for (int r = 0; r < 4; ++r) {
          float v = sc[nf][r] * scale;
          if (diag && kvg > qg0 + r) v = -__builtin_inff();
          sc[nf][r] = v;
        }
      }

      float mnew[4], alpha[4], rs[4];
#pragma unroll
      for (int r = 0; r < 4; ++r) {
        float v = fmaxf(fmaxf(sc[0][r], sc[1][r]), fmaxf(sc[2][r], sc[3][r]));
#pragma unroll
        for (int sh = 1; sh < 16; sh <<= 1) v = fmaxf(v, __shfl_xor(v, sh));
        mnew[r] = fmaxf(m[r], v);
        alpha[r] = __expf(m[r] - mnew[r]);
        m[r] = mnew[r];
        rs[r] = 0.f;
      }

      bf16* pw = &pld[wave * 16 * 72];
#pragma unroll
      for (int nf = 0; nf < 4; ++nf)
#pragma unroll
        for (int r = 0; r < 4; ++r) {
          float p = __expf(sc[nf][r] - mnew[r]);
          bf16 pb = (bf16)p;
          pw[(lh * 4 + r) * 72 + nf * 16 + l15] = pb;
          rs[r] += (float)pb;
        }
#pragma unroll
      for (int r = 0; r < 4; ++r) {
        float v = rs[r];
#pragma unroll
        for (int sh = 1; sh < 16; sh <<= 1) v += __shfl_xor(v, sh);
        lsum[r] = lsum[r] * alpha[r] + v;
      }
#pragma unroll
      for (int i2 = 0; i2 < 8; ++i2)
#pragma unroll
        for (int r = 0; r < 4; ++r) o[i2][r] *= alpha[r];

      __builtin_amdgcn_s_setprio(1);
#pragma unroll
      for (int kkv = 0; kkv < 2; ++kkv) {
        bf16x8 pa = *(const bf16x8*)&pw[l15 * 72 + kkv * 32 + lh * 8];
#pragma unroll
        for (int df = 0; df < 8; ++df) {
          int dv = df * 16 + l15;
          int klin = (kkv * 32 + lh * 8) ^ ((dv & 7) << 3);
          bf16x8 vb = *(const bf16x8*)&vls[buf][dv * 64 + klin];
          o[df] = __builtin_amdgcn_mfma_f32_16x16x32_bf16(pa, vb, o[df], 0, 0, 0);
        }
      }
      __builtin_amdgcn_s_setprio(0);
    }
    __syncthreads();
  }

  // merge: group1 publishes (o, m, l); group0 combines and stores.
  if (grp == 1) {
#pragma unroll
    for (int df = 0; df < 8; ++df)
#pragma unroll
      for (int r = 0; r < 4; ++r)
        oml[(w4 * 16 + lh * 4 + r) * 128 + df * 16 + l15] = o[df][r];
    if (l15 == 0) {
#pragma unroll
      for (int r = 0; r < 4; ++r) {
        mls[w4 * 16 + lh * 4 + r] = m[r];
        lls[w4 * 16 + lh * 4 + r] = lsum[r];
      }
    }
  }
  __syncthreads();
  if (grp == 0) {
#pragma unroll
    for (int r = 0; r < 4; ++r) {
      int row = w4 * 16 + lh * 4 + r;
      float m1 = mls[row], l1 = lls[row];
      float mm = fmaxf(m[r], m1);
      float s0 = __expf(m[r] - mm);
      float s1 = __expf(m1 - mm);
      float inv = 1.0f / (lsum[r] * s0 + l1 * s1);
      float* op = out + (size_t)(batch * S_LEN + qbase + row) * HD;
#pragma unroll
      for (int df = 0; df < 8; ++df)
        op[df * 16 + l15] =
            (o[df][r] * s0 + oml[row * 128 + df * 16 + l15] * s1) * inv;
    }
  }
}

extern "C" void kernel_launch(void* const* d_in, const int* in_sizes, int n_in,
                              void* d_out, int out_size, void* d_ws, size_t ws_size,
                              hipStream_t stream) {
  const float* x = (const float*)d_in[0];
  const float* Wq = (const float*)d_in[1];
  const float* bq = (const float*)d_in[2];
  const float* Wk = (const float*)d_in[3];
  const float* bk = (const float*)d_in[4];
  const float* Wv = (const float*)d_in[5];
  const float* bv = (const float*)d_in[6];
  float* out = (float*)d_out;

  char* ws = (char*)d_ws;
  bf16* wt  = (bf16*)(ws);                       // 1.5 MB  (Wt, swizzled)
  bf16* Qw  = (bf16*)(ws + (size_t)(2u << 20));  // 4 MB
  bf16* Kw  = (bf16*)(ws + (size_t)(6u << 20));  // 4 MB
  bf16* Vtw = (bf16*)(ws + (size_t)(10u << 20)); // 4 MB

  hipLaunchKernelGGL(k_prep, dim3(192), dim3(256), 0, stream, Wq, Wk, Wv, wt);
  hipLaunchKernelGGL(k_qkv, dim3(768), dim3(256), 0, stream, x, wt, bq, bk, bv,
                     Qw, Kw, Vtw);
  hipLaunchKernelGGL(k_attn, dim3(256), dim3(512), 0, stream, Qw, Kw, Vtw, out);
}

// Round 12
// 101.606 us; speedup vs baseline: 1.1363x; 1.1363x over previous
//
#include <hip/hip_runtime.h>

typedef __bf16 bf16;
typedef __bf16 bf16x8 __attribute__((ext_vector_type(8)));
typedef float f32x4 __attribute__((ext_vector_type(4)));

#define S_LEN 2048
#define EMBD 2048
#define HD 128

__device__ inline void gload16(const void* g, void* l) {
  __builtin_amdgcn_global_load_lds(
      (const __attribute__((address_space(1))) unsigned int*)g,
      (__attribute__((address_space(3))) unsigned int*)l, 16, 0, 0);
}

// ---------------------------------------------------------------------------
// K0: Wt[mat][n][k] = bf16( W[ (k&~63) | ((k&63) ^ ((n&7)<<3)) ][n] )
// Coalesced via LDS transpose: block = (mat, n-tile of 64, k-tile of 64).
// ---------------------------------------------------------------------------
__global__ __launch_bounds__(256) void k_prep(const float* __restrict__ Wq,
                                              const float* __restrict__ Wk,
                                              const float* __restrict__ Wv,
                                              bf16* __restrict__ wt) {
  __shared__ bf16 wls[64 * 72];  // [k][n] padded

  const int t = threadIdx.x;
  const int bid = blockIdx.x;           // 3 * 2 * 32 = 192 blocks
  const int mat = bid >> 6;
  const int nt = bid & 1;
  const int kt = (bid & 63) >> 1;
  const int k0 = kt * 64, n0 = nt * 64;
  const float* W = (mat == 0) ? Wq : ((mat == 1) ? Wk : Wv);

#pragma unroll
  for (int i = 0; i < 4; ++i) {
    int e = i * 256 + t;          // 0..1023
    int r = e >> 4, c4 = e & 15;  // row k, 4-col group
    float4 v = *(const float4*)(W + (size_t)(k0 + r) * HD + n0 + c4 * 4);
    union { bf16 h[4]; uint2 u; } p;
    p.h[0] = (bf16)v.x; p.h[1] = (bf16)v.y;
    p.h[2] = (bf16)v.z; p.h[3] = (bf16)v.w;
    *(uint2*)&wls[r * 72 + c4 * 4] = p.u;
  }
  __syncthreads();
#pragma unroll
  for (int i = 0; i < 2; ++i) {
    int slot = i * 256 + t;  // 0..511: n_loc = slot>>3, kq = slot&7
    int n_loc = slot >> 3, kq = slot & 7;
    int n = n0 + n_loc;
    int kbase = (kq * 8) ^ ((n & 7) << 3);
    union { bf16 h[8]; uint4 u; } p;
#pragma unroll
    for (int j = 0; j < 8; ++j) p.h[j] = wls[(kbase + j) * 72 + n_loc];
    *(uint4*)&wt[(size_t)(mat * HD + n) * EMBD + k0 + kq * 8] = p.u;
  }
}

// ---------------------------------------------------------------------------
// K1: fused QKV GEMM + bias + RoPE. R5-exact geometry (measured 80 us):
// BM=64, BN=128, BK=64; by = 0:Q,1:K,2:V; 256 thr / 4 waves (2m x 2n),
// wave-tile 32x64, dbuf LDS 50.4 KB -> 3 blocks/CU, grid 768.
// NEW: (1) start-stagger by `by` (co-resident blocks carry distinct by) to
// break the 3-block barrier-cadence convoy; (2) setprio around MFMA.
// ---------------------------------------------------------------------------
__global__ __launch_bounds__(256, 3) void k_qkv(
    const float* __restrict__ x, const bf16* __restrict__ wt,
    const float* __restrict__ bq, const float* __restrict__ bk,
    const float* __restrict__ bv, bf16* __restrict__ Qw, bf16* __restrict__ Kw,
    bf16* __restrict__ Vtw) {
  __shared__ __align__(16) bf16 xs[2][64 * 72];    // 18.4 KB
  __shared__ __align__(16) bf16 wts[2][128 * 64];  // 32 KB

  const int tid = threadIdx.x;
  const int lane = tid & 63;
  const int wave = tid >> 6;
  const int wm = wave >> 1;  // 0..1 m-half
  const int wn = wave & 1;   // 0..1 n-half
  const int l15 = lane & 15;
  const int lh = lane >> 4;  // 0..3

  const int bid = blockIdx.x;
  const int g = bid >> 3;
  const int by = g % 3;            // 0:Q 1:K 2:V
  const int mt = (bid & 7) + 8 * (g / 3);
  const int row0 = mt * 64;

  // convoy-breaker: co-resident blocks have distinct by -> offset their
  // barrier cadence by ~1/3 step so one block's MFMA covers another's drain.
#pragma unroll 1
  for (int i = 0; i < by; ++i) __builtin_amdgcn_s_sleep(4);

  f32x4 acc[2][4];
#pragma unroll
  for (int mf = 0; mf < 2; ++mf)
#pragma unroll
    for (int f = 0; f < 4; ++f) acc[mf][f] = {};

  // staging geometry (loop-invariant)
  int xr_[4], xk_[4];
  const float* xp_[4];
#pragma unroll
  for (int i = 0; i < 4; ++i) {
    int e = (i * 256 + tid) * 4;
    xr_[i] = e >> 6;
    xk_[i] = e & 63;
    xp_[i] = x + (size_t)(row0 + xr_[i]) * EMBD + xk_[i];
  }
  const bf16* wp_[4];
  int we_[4];
#pragma unroll
  for (int i = 0; i < 4; ++i) {
    int e = (i * 256 + tid) * 8;
    int np = e >> 6, k = e & 63;
    wp_[i] = wt + (size_t)(by * 128 + np) * EMBD + k;
    we_[i] = e;
  }

  auto stage_issue = [&](int ks, int buf, float4* xr) {
#pragma unroll
    for (int i = 0; i < 4; ++i) xr[i] = *(const float4*)(xp_[i] + ks * 64);
#pragma unroll
    for (int i = 0; i < 4; ++i) gload16(wp_[i] + ks * 64, &wts[buf][we_[i]]);
  };
  auto xwrite = [&](int buf, const float4* xr) {
#pragma unroll
    for (int i = 0; i < 4; ++i) {
      union { bf16 h[4]; uint2 u; } p;
      p.h[0] = (bf16)xr[i].x; p.h[1] = (bf16)xr[i].y;
      p.h[2] = (bf16)xr[i].z; p.h[3] = (bf16)xr[i].w;
      *(uint2*)&xs[buf][xr_[i] * 72 + xk_[i]] = p.u;
    }
  };

  {
    float4 xr[4];
    stage_issue(0, 0, xr);
    xwrite(0, xr);
  }
  __syncthreads();

  for (int ks = 0; ks < EMBD / 64; ++ks) {
    const int c = ks & 1, pbuf = c ^ 1;
    float4 xr[4];
    if (ks < EMBD / 64 - 1) stage_issue(ks + 1, pbuf, xr);

    __builtin_amdgcn_s_setprio(1);
#pragma unroll
    for (int kk = 0; kk < 2; ++kk) {
      bf16x8 a[2];
#pragma unroll
      for (int mf = 0; mf < 2; ++mf)
        a[mf] = *(const bf16x8*)&xs[c][(wm * 32 + mf * 16 + l15) * 72 + kk * 32 + lh * 8];
#pragma unroll
      for (int f = 0; f < 4; ++f) {
        int col = (f & 1) * 16 + (f >> 1) * 64 + wn * 32 + l15;
        int klin = (kk * 32 + lh * 8) ^ ((col & 7) << 3);
        bf16x8 b = *(const bf16x8*)&wts[c][col * 64 + klin];
#pragma unroll
        for (int mf = 0; mf < 2; ++mf)
          acc[mf][f] =
              __builtin_amdgcn_mfma_f32_16x16x32_bf16(a[mf], b, acc[mf][f], 0, 0, 0);
      }
    }
    __builtin_amdgcn_s_setprio(0);

    if (ks < EMBD / 64 - 1) xwrite(pbuf, xr);
    __syncthreads();
  }

  const int bb = row0 >> 11;
  const int s0 = row0 & (S_LEN - 1);

  if (by < 2) {  // Q or K: bias + RoPE, direct store
    const float* bias = (by == 0) ? bq : bk;
#pragma unroll
    for (int fp = 0; fp < 2; ++fp) {
      const int colA = wn * 32 + fp * 16 + l15;  // 0..63
      const int colB = colA + 64;
      float biasA = bias[colA], biasB = bias[colB];
      float invf = exp2f((float)colA * -0.20762050593046014f);  // -log2(1e4)/64
#pragma unroll
      for (int mf = 0; mf < 2; ++mf) {
#pragma unroll
        for (int r = 0; r < 4; ++r) {
          int s = s0 + wm * 32 + mf * 16 + lh * 4 + r;
          float xa_ = acc[mf][fp][r] + biasA;
          float xb_ = acc[mf][fp + 2][r] + biasB;
          float sn, cs;
          sincosf((float)s * invf, &sn, &cs);
          float oa = xa_ * cs - xb_ * sn;
          float ob = xa_ * sn + xb_ * cs;
          if (by == 0) {
            Qw[(size_t)(bb * S_LEN + s) * HD + colA] = (bf16)oa;
            Qw[(size_t)(bb * S_LEN + s) * HD + colB] = (bf16)ob;
          } else {
            int sw = (s & 7) << 3;
            Kw[(size_t)(bb * S_LEN + s) * HD + (colA ^ sw)] = (bf16)oa;
            Kw[(size_t)(bb * S_LEN + s) * HD + (colB ^ sw)] = (bf16)ob;
          }
        }
      }
    }
  } else {  // V: bias, transpose through LDS (xs arena), swizzled store
    bf16* vstage = &xs[0][0];  // 9216 elems = 128 x 72
#pragma unroll
    for (int f = 0; f < 4; ++f) {
      int dv = (f & 1) * 16 + (f >> 1) * 64 + wn * 32 + l15;
      float biasV = bv[dv];
#pragma unroll
      for (int mf = 0; mf < 2; ++mf)
#pragma unroll
        for (int r = 0; r < 4; ++r) {
          int mrow = wm * 32 + mf * 16 + lh * 4 + r;
          vstage[dv * 72 + mrow] = (bf16)(acc[mf][f][r] + biasV);
        }
    }
    __syncthreads();
#pragma unroll
    for (int i = 0; i < 4; ++i) {
      int c = i * 256 + tid;  // 0..1023: dv = c>>3, kq = c&7
      int dv = c >> 3, kq = c & 7;
      uint4 v = *(const uint4*)&vstage[dv * 72 + kq * 8];
      int slot = (kq * 8) ^ ((dv & 7) << 3);
      *(uint4*)&Vtw[((size_t)(bb * HD + dv) << 11) + s0 + slot] = v;
    }
  }
}

// ---------------------------------------------------------------------------
// K2: causal flash attention. 512 thr = 2 groups x 4 waves; groups split the
// KV range (even/odd tiles) and merge (m,l,o) via LDS at the end.
// ---------------------------------------------------------------------------
__global__ __launch_bounds__(512) void k_attn(
    const bf16* __restrict__ Qw, const bf16* __restrict__ Kw,
    const bf16* __restrict__ Vtw, float* __restrict__ out) {
  __shared__ __align__(16) char arena[131072];       // 128 KB: K/V dbuf x 2 grp
  __shared__ __align__(16) bf16 pld[8 * 16 * 72];    // 18.4 KB
  __shared__ float mls[64], lls[64];

  bf16(*kls)[64 * 128] = (bf16(*)[64 * 128])arena;             // [grp*2+buf]
  bf16(*vls)[128 * 64] = (bf16(*)[128 * 64])(arena + 65536);   // [grp*2+buf]
  float* oml = (float*)arena;  // merge area: 64 x 128 f32 (aliases kls[0..1])

  const int tid = threadIdx.x;
  const int lane = tid & 63;
  const int wave = tid >> 6;
  const int grp = wave >> 2;
  const int w4 = wave & 3;
  const int l15 = lane & 15;
  const int lh = lane >> 4;
  const int t256 = tid & 255;

  const int bid = blockIdx.x;
  const int batch = bid & 7;  // batch == XCD (round-robin) -> KV L2 locality
  const int qt = 31 - (bid >> 3);
  const int qbase = qt * 64;
  const int nt = qt + 1;
  const int mysteps = (nt - grp + 1) >> 1;  // grp0: ceil(nt/2), grp1: floor
  const int maxst = (nt + 1) >> 1;

  const bf16* kbat = Kw + (size_t)(batch * S_LEN) * HD;
  const bf16* vbat = Vtw + ((size_t)(batch * HD) << 11);

  auto stage = [&](int t, int buf) {
    bf16* kdst = kls[grp * 2 + buf];
    bf16* vdst = vls[grp * 2 + buf];
    const bf16* kbase = kbat + (size_t)(t * 64) * HD;
#pragma unroll
    for (int i = 0; i < 4; ++i) {
      int c = i * 256 + t256;
      gload16(kbase + c * 8, kdst + c * 8);
    }
    const bf16* vbase = vbat + t * 64;
#pragma unroll
    for (int i = 0; i < 4; ++i) {
      int c = i * 256 + t256;
      int dv = c >> 3, kq = (c & 7) * 8;
      gload16(vbase + ((size_t)dv << 11) + kq, vdst + c * 8);
    }
  };

  bf16x8 qa[4];
  {
    const bf16* qptr = Qw + (size_t)(batch * S_LEN + qbase + w4 * 16 + l15) * HD;
#pragma unroll
    for (int kk = 0; kk < 4; ++kk) qa[kk] = *(const bf16x8*)(qptr + kk * 32 + lh * 8);
  }

  f32x4 o[8];
#pragma unroll
  for (int i = 0; i < 8; ++i) o[i] = {};
  float m[4], lsum[4];
#pragma unroll
  for (int r = 0; r < 4; ++r) { m[r] = -__builtin_inff(); lsum[r] = 0.f; }

  const float scale = 0.08838834764831845f;  // 1/sqrt(128)

  if (mysteps > 0) stage(grp, 0);
  __syncthreads();

  for (int i = 0; i < maxst; ++i) {
    if (i + 1 < mysteps) stage(2 * (i + 1) + grp, (i + 1) & 1);
    if (i < mysteps) {
      const int t = 2 * i + grp;
      const int buf = grp * 2 + (i & 1);
      const int kv0 = t * 64;

      f32x4 sc[4];
#pragma unroll
      for (int nf = 0; nf < 4; ++nf) sc[nf] = {};
      __builtin_amdgcn_s_setprio(1);
#pragma unroll
      for (int kk = 0; kk < 4; ++kk) {
#pragma unroll
        for (int nf = 0; nf < 4; ++nf) {
          int row = nf * 16 + l15;
          int dlin = (kk * 32 + lh * 8) ^ ((row & 7) << 3);
          bf16x8 kb = *(const bf16x8*)&kls[buf][row * 128 + dlin];
          sc[nf] = __builtin_amdgcn_mfma_f32_16x16x32_bf16(qa[kk], kb, sc[nf], 0, 0, 0);
        }
      }
      __builtin_amdgcn_s_setprio(0);

      const bool diag = (t == qt);
      const int qg0 = qbase + w4 * 16 + lh * 4;
#pragma unroll
      for (int nf = 0; nf < 4; ++nf) {
        int kvg = kv0 + nf * 16 + l15;
#pragma unroll
        for (int r = 0; r < 4; ++r) {
          float v = sc[nf][r] * scale;
          if (diag && kvg > qg0 + r) v = -__builtin_inff();
          sc[nf][r] = v;
        }
      }

      float mnew[4], alpha[4], rs[4];
#pragma unroll
      for (int r = 0; r < 4; ++r) {
        float v = fmaxf(fmaxf(sc[0][r], sc[1][r]), fmaxf(sc[2][r], sc[3][r]));
#pragma unroll
        for (int sh = 1; sh < 16; sh <<= 1) v = fmaxf(v, __shfl_xor(v, sh));
        mnew[r] = fmaxf(m[r], v);
        alpha[r] = __expf(m[r] - mnew[r]);
        m[r] = mnew[r];
        rs[r] = 0.f;
      }

      bf16* pw = &pld[wave * 16 * 72];
#pragma unroll
      for (int nf = 0; nf < 4; ++nf)
#pragma unroll
        for (int r = 0; r < 4; ++r) {
          float p = __expf(sc[nf][r] - mnew[r]);
          bf16 pb = (bf16)p;
          pw[(lh * 4 + r) * 72 + nf * 16 + l15] = pb;
          rs[r] += (float)pb;
        }
#pragma unroll
      for (int r = 0; r < 4; ++r) {
        float v = rs[r];
#pragma unroll
        for (int sh = 1; sh < 16; sh <<= 1) v += __shfl_xor(v, sh);
        lsum[r] = lsum[r] * alpha[r] + v;
      }
#pragma unroll
      for (int i2 = 0; i2 < 8; ++i2)
#pragma unroll
        for (int r = 0; r < 4; ++r) o[i2][r] *= alpha[r];

      __builtin_amdgcn_s_setprio(1);
#pragma unroll
      for (int kkv = 0; kkv < 2; ++kkv) {
        bf16x8 pa = *(const bf16x8*)&pw[l15 * 72 + kkv * 32 + lh * 8];
#pragma unroll
        for (int df = 0; df < 8; ++df) {
          int dv = df * 16 + l15;
          int klin = (kkv * 32 + lh * 8) ^ ((dv & 7) << 3);
          bf16x8 vb = *(const bf16x8*)&vls[buf][dv * 64 + klin];
          o[df] = __builtin_amdgcn_mfma_f32_16x16x32_bf16(pa, vb, o[df], 0, 0, 0);
        }
      }
      __builtin_amdgcn_s_setprio(0);
    }
    __syncthreads();
  }

  // merge: group1 publishes (o, m, l); group0 combines and stores.
  if (grp == 1) {
#pragma unroll
    for (int df = 0; df < 8; ++df)
#pragma unroll
      for (int r = 0; r < 4; ++r)
        oml[(w4 * 16 + lh * 4 + r) * 128 + df * 16 + l15] = o[df][r];
    if (l15 == 0) {
#pragma unroll
      for (int r = 0; r < 4; ++r) {
        mls[w4 * 16 + lh * 4 + r] = m[r];
        lls[w4 * 16 + lh * 4 + r] = lsum[r];
      }
    }
  }
  __syncthreads();
  if (grp == 0) {
#pragma unroll
    for (int r = 0; r < 4; ++r) {
      int row = w4 * 16 + lh * 4 + r;
      float m1 = mls[row], l1 = lls[row];
      float mm = fmaxf(m[r], m1);
      float s0 = __expf(m[r] - mm);
      float s1 = __expf(m1 - mm);
      float inv = 1.0f / (lsum[r] * s0 + l1 * s1);
      float* op = out + (size_t)(batch * S_LEN + qbase + row) * HD;
#pragma unroll
      for (int df = 0; df < 8; ++df)
        op[df * 16 + l15] =
            (o[df][r] * s0 + oml[row * 128 + df * 16 + l15] * s1) * inv;
    }
  }
}

extern "C" void kernel_launch(void* const* d_in, const int* in_sizes, int n_in,
                              void* d_out, int out_size, void* d_ws, size_t ws_size,
                              hipStream_t stream) {
  const float* x = (const float*)d_in[0];
  const float* Wq = (const float*)d_in[1];
  const float* bq = (const float*)d_in[2];
  const float* Wk = (const float*)d_in[3];
  const float* bk = (const float*)d_in[4];
  const float* Wv = (const float*)d_in[5];
  const float* bv = (const float*)d_in[6];
  float* out = (float*)d_out;

  char* ws = (char*)d_ws;
  bf16* wt  = (bf16*)(ws);                       // 1.5 MB  (Wt, swizzled)
  bf16* Qw  = (bf16*)(ws + (size_t)(2u << 20));  // 4 MB
  bf16* Kw  = (bf16*)(ws + (size_t)(6u << 20));  // 4 MB
  bf16* Vtw = (bf16*)(ws + (size_t)(10u << 20)); // 4 MB

  hipLaunchKernelGGL(k_prep, dim3(192), dim3(256), 0, stream, Wq, Wk, Wv, wt);
  hipLaunchKernelGGL(k_qkv, dim3(768), dim3(256), 0, stream, x, wt, bq, bk, bv,
                     Qw, Kw, Vtw);
  hipLaunchKernelGGL(k_attn, dim3(256), dim3(512), 0, stream, Qw, Kw, Vtw, out);
}

// Round 13
// 98.205 us; speedup vs baseline: 1.1757x; 1.0346x over previous
//
#include <hip/hip_runtime.h>

typedef __bf16 bf16;
typedef __bf16 bf16x8 __attribute__((ext_vector_type(8)));
typedef float f32x4 __attribute__((ext_vector_type(4)));

#define S_LEN 2048
#define EMBD 2048
#define HD 128

__device__ inline void gload16(const void* g, void* l) {
  __builtin_amdgcn_global_load_lds(
      (const __attribute__((address_space(1))) unsigned int*)g,
      (__attribute__((address_space(3))) unsigned int*)l, 16, 0, 0);
}

// ---------------------------------------------------------------------------
// K0: Wt[mat][n][k] = bf16( W[ (k&~63) | ((k&63) ^ ((n&7)<<3)) ][n] )
// Coalesced via LDS transpose: block = (mat, n-tile of 64, k-tile of 64).
// ---------------------------------------------------------------------------
__global__ __launch_bounds__(256) void k_prep(const float* __restrict__ Wq,
                                              const float* __restrict__ Wk,
                                              const float* __restrict__ Wv,
                                              bf16* __restrict__ wt) {
  __shared__ bf16 wls[64 * 72];  // [k][n] padded

  const int t = threadIdx.x;
  const int bid = blockIdx.x;           // 3 * 2 * 32 = 192 blocks
  const int mat = bid >> 6;
  const int nt = bid & 1;
  const int kt = (bid & 63) >> 1;
  const int k0 = kt * 64, n0 = nt * 64;
  const float* W = (mat == 0) ? Wq : ((mat == 1) ? Wk : Wv);

#pragma unroll
  for (int i = 0; i < 4; ++i) {
    int e = i * 256 + t;          // 0..1023
    int r = e >> 4, c4 = e & 15;  // row k, 4-col group
    float4 v = *(const float4*)(W + (size_t)(k0 + r) * HD + n0 + c4 * 4);
    union { bf16 h[4]; uint2 u; } p;
    p.h[0] = (bf16)v.x; p.h[1] = (bf16)v.y;
    p.h[2] = (bf16)v.z; p.h[3] = (bf16)v.w;
    *(uint2*)&wls[r * 72 + c4 * 4] = p.u;
  }
  __syncthreads();
#pragma unroll
  for (int i = 0; i < 2; ++i) {
    int slot = i * 256 + t;  // 0..511: n_loc = slot>>3, kq = slot&7
    int n_loc = slot >> 3, kq = slot & 7;
    int n = n0 + n_loc;
    int kbase = (kq * 8) ^ ((n & 7) << 3);
    union { bf16 h[8]; uint4 u; } p;
#pragma unroll
    for (int j = 0; j < 8; ++j) p.h[j] = wls[(kbase + j) * 72 + n_loc];
    *(uint4*)&wt[(size_t)(mat * HD + n) * EMBD + k0 + kq * 8] = p.u;
  }
}

// ---------------------------------------------------------------------------
// K1: fused QKV GEMM + bias + RoPE. R3-resurrection: BM=64, BN=192, BK=64;
// by0 = Q + V[0:64], by1 = K + V[64:128] -> x staged 2x not 3x (volume
// 640 MB vs 768 MB; time tracks staged volume / ~9.6 TB/s across R2-R12).
// 512 thr / 8 waves (2m x 4n), wave-tile 32x48 (acc[2][3]). xs stored
// bf16-SWIZZLED (col ^ (row&7)<<3, no pad) -> LDS 16+48 = 64 KB ->
// 2 blocks/CU, grid 512 = exactly 2/CU (16 waves/CU).
// ---------------------------------------------------------------------------
__global__ __launch_bounds__(512, 4) void k_qkv(
    const float* __restrict__ x, const bf16* __restrict__ wt,
    const float* __restrict__ bq, const float* __restrict__ bk,
    const float* __restrict__ bv, bf16* __restrict__ Qw, bf16* __restrict__ Kw,
    bf16* __restrict__ Vtw) {
  __shared__ __align__(16) bf16 xs[2][64 * 64];    // 16 KB, XOR-swizzled
  __shared__ __align__(16) bf16 wts[2][192 * 64];  // 48 KB, swizzle pre-baked

  const int tid = threadIdx.x;
  const int lane = tid & 63;
  const int wave = tid >> 6;
  const int wm = wave >> 2;  // 0..1: 32-row half
  const int wn = wave & 3;   // 0..3: 16-col slice
  const int l15 = lane & 15;
  const int lh = lane >> 4;  // 0..3

  // bid = xcd + 8*g: by = g&1, mt = xcd*32 + (g>>1). The by-pair of one
  // m-tile shares an XCD -> x L2 reuse.
  const int bid = blockIdx.x;
  const int g = bid >> 3;
  const int by = g & 1;  // 0: Q+Vlo, 1: K+Vhi
  const int mt = (bid & 7) * 32 + (g >> 1);
  const int row0 = mt * 64;

  f32x4 acc[2][3];  // [mf][f]: f0 = col wn*16, f1 = +64 (rope pair), f2 = V
#pragma unroll
  for (int mf = 0; mf < 2; ++mf)
#pragma unroll
    for (int f = 0; f < 3; ++f) acc[mf][f] = {};

  // x staging: 64x64 f32 = 2 float4/thread, coalesced
  int xr_[2], xk_[2];
  const float* xp_[2];
#pragma unroll
  for (int i = 0; i < 2; ++i) {
    int e = (i * 512 + tid) * 4;
    xr_[i] = e >> 6;
    xk_[i] = e & 63;
    xp_[i] = x + (size_t)(row0 + xr_[i]) * EMBD + xk_[i];
  }
  // B staging: 192x64 bf16 = 3 gload16/thread
  const bf16* wp_[3];
  int we_[3];
#pragma unroll
  for (int i = 0; i < 3; ++i) {
    int e = (i * 512 + tid) * 8;
    int np = e >> 6, k = e & 63;  // lds row 0..191
    int ng = (np < 128) ? by * 128 + np : 256 + by * 64 + (np - 128);
    wp_[i] = wt + (size_t)ng * EMBD + k;
    we_[i] = e;
  }

  auto stage_issue = [&](int ks, int buf, float4* xr) {
#pragma unroll
    for (int i = 0; i < 2; ++i) xr[i] = *(const float4*)(xp_[i] + ks * 64);
#pragma unroll
    for (int i = 0; i < 3; ++i) gload16(wp_[i] + ks * 64, &wts[buf][we_[i]]);
  };
  auto xwrite = [&](int buf, const float4* xr) {
#pragma unroll
    for (int i = 0; i < 2; ++i) {
      union { bf16 h[4]; uint2 u; } p;
      p.h[0] = (bf16)xr[i].x; p.h[1] = (bf16)xr[i].y;
      p.h[2] = (bf16)xr[i].z; p.h[3] = (bf16)xr[i].w;
      // XOR-swizzle (bits 3..5 of elem idx); xk_ is 4-aligned, XOR bits >= 8
      *(uint2*)&xs[buf][xr_[i] * 64 + (xk_[i] ^ ((xr_[i] & 7) << 3))] = p.u;
    }
  };

  {
    float4 xr[2];
    stage_issue(0, 0, xr);
    xwrite(0, xr);
  }
  __syncthreads();

  for (int ks = 0; ks < EMBD / 64; ++ks) {
    const int c = ks & 1, pbuf = c ^ 1;
    float4 xr[2];
    if (ks < EMBD / 64 - 1) stage_issue(ks + 1, pbuf, xr);

    __builtin_amdgcn_s_setprio(1);
#pragma unroll
    for (int kk = 0; kk < 2; ++kk) {
      bf16x8 a[2];
#pragma unroll
      for (int mf = 0; mf < 2; ++mf) {
        int row = wm * 32 + mf * 16 + l15;
        a[mf] = *(const bf16x8*)&xs[c][row * 64 + ((kk * 32 + lh * 8) ^ ((row & 7) << 3))];
      }
#pragma unroll
      for (int f = 0; f < 3; ++f) {
        int col = (f < 2) ? (f * 64 + wn * 16 + l15) : (128 + wn * 16 + l15);
        int klin = (kk * 32 + lh * 8) ^ ((col & 7) << 3);
        bf16x8 b = *(const bf16x8*)&wts[c][col * 64 + klin];
#pragma unroll
        for (int mf = 0; mf < 2; ++mf)
          acc[mf][f] =
              __builtin_amdgcn_mfma_f32_16x16x32_bf16(a[mf], b, acc[mf][f], 0, 0, 0);
      }
    }
    __builtin_amdgcn_s_setprio(0);

    if (ks < EMBD / 64 - 1) xwrite(pbuf, xr);
    __syncthreads();
  }

  const int bb = row0 >> 11;
  const int s0 = row0 & (S_LEN - 1);

  // f0/f1: RoPE pair (Q for by0, K for by1)
  {
    const int colA = wn * 16 + l15;  // 0..63
    const int colB = colA + 64;
    const float* bias = (by == 0) ? bq : bk;
    float biasA = bias[colA], biasB = bias[colB];
    float invf = exp2f((float)colA * -0.20762050593046014f);  // -log2(1e4)/64
#pragma unroll
    for (int mf = 0; mf < 2; ++mf) {
#pragma unroll
      for (int r = 0; r < 4; ++r) {
        int s = s0 + wm * 32 + mf * 16 + lh * 4 + r;
        float xa_ = acc[mf][0][r] + biasA;
        float xb_ = acc[mf][1][r] + biasB;
        float sn, cs;
        sincosf((float)s * invf, &sn, &cs);
        float oa = xa_ * cs - xb_ * sn;
        float ob = xa_ * sn + xb_ * cs;
        if (by == 0) {
          Qw[(size_t)(bb * S_LEN + s) * HD + colA] = (bf16)oa;
          Qw[(size_t)(bb * S_LEN + s) * HD + colB] = (bf16)ob;
        } else {
          int sw = (s & 7) << 3;
          Kw[(size_t)(bb * S_LEN + s) * HD + (colA ^ sw)] = (bf16)oa;
          Kw[(size_t)(bb * S_LEN + s) * HD + (colB ^ sw)] = (bf16)ob;
        }
      }
    }
  }
  // f2: V (no rope) -> LDS transpose stage (xs arena: 64*72 = 4608 elems)
  {
    bf16* vstage = &xs[0][0];
    const int dvl = wn * 16 + l15;  // 0..63 local
    float biasV = bv[by * 64 + dvl];
#pragma unroll
    for (int mf = 0; mf < 2; ++mf)
#pragma unroll
      for (int r = 0; r < 4; ++r) {
        int mrow = wm * 32 + mf * 16 + lh * 4 + r;
        vstage[dvl * 72 + mrow] = (bf16)(acc[mf][2][r] + biasV);
      }
    __syncthreads();
    {  // transposed V store: 512 chunks of 16B, 1 per thread
      int dvl2 = tid >> 3, kq = tid & 7;
      uint4 v = *(const uint4*)&vstage[dvl2 * 72 + kq * 8];
      int dv = by * 64 + dvl2;
      int slot = (kq * 8) ^ ((dvl2 & 7) << 3);
      *(uint4*)&Vtw[((size_t)(bb * HD + dv) << 11) + s0 + slot] = v;
    }
  }
}

// ---------------------------------------------------------------------------
// K2: causal flash attention. 512 thr = 2 groups x 4 waves; groups split the
// KV range (even/odd tiles) and merge (m,l,o) via LDS at the end.
// ---------------------------------------------------------------------------
__global__ __launch_bounds__(512) void k_attn(
    const bf16* __restrict__ Qw, const bf16* __restrict__ Kw,
    const bf16* __restrict__ Vtw, float* __restrict__ out) {
  __shared__ __align__(16) char arena[131072];       // 128 KB: K/V dbuf x 2 grp
  __shared__ __align__(16) bf16 pld[8 * 16 * 72];    // 18.4 KB
  __shared__ float mls[64], lls[64];

  bf16(*kls)[64 * 128] = (bf16(*)[64 * 128])arena;             // [grp*2+buf]
  bf16(*vls)[128 * 64] = (bf16(*)[128 * 64])(arena + 65536);   // [grp*2+buf]
  float* oml = (float*)arena;  // merge area: 64 x 128 f32 (aliases kls[0..1])

  const int tid = threadIdx.x;
  const int lane = tid & 63;
  const int wave = tid >> 6;
  const int grp = wave >> 2;
  const int w4 = wave & 3;
  const int l15 = lane & 15;
  const int lh = lane >> 4;
  const int t256 = tid & 255;

  const int bid = blockIdx.x;
  const int batch = bid & 7;  // batch == XCD (round-robin) -> KV L2 locality
  const int qt = 31 - (bid >> 3);
  const int qbase = qt * 64;
  const int nt = qt + 1;
  const int mysteps = (nt - grp + 1) >> 1;  // grp0: ceil(nt/2), grp1: floor
  const int maxst = (nt + 1) >> 1;

  const bf16* kbat = Kw + (size_t)(batch * S_LEN) * HD;
  const bf16* vbat = Vtw + ((size_t)(batch * HD) << 11);

  auto stage = [&](int t, int buf) {
    bf16* kdst = kls[grp * 2 + buf];
    bf16* vdst = vls[grp * 2 + buf];
    const bf16* kbase = kbat + (size_t)(t * 64) * HD;
#pragma unroll
    for (int i = 0; i < 4; ++i) {
      int c = i * 256 + t256;
      gload16(kbase + c * 8, kdst + c * 8);
    }
    const bf16* vbase = vbat + t * 64;
#pragma unroll
    for (int i = 0; i < 4; ++i) {
      int c = i * 256 + t256;
      int dv = c >> 3, kq = (c & 7) * 8;
      gload16(vbase + ((size_t)dv << 11) + kq, vdst + c * 8);
    }
  };

  bf16x8 qa[4];
  {
    const bf16* qptr = Qw + (size_t)(batch * S_LEN + qbase + w4 * 16 + l15) * HD;
#pragma unroll
    for (int kk = 0; kk < 4; ++kk) qa[kk] = *(const bf16x8*)(qptr + kk * 32 + lh * 8);
  }

  f32x4 o[8];
#pragma unroll
  for (int i = 0; i < 8; ++i) o[i] = {};
  float m[4], lsum[4];
#pragma unroll
  for (int r = 0; r < 4; ++r) { m[r] = -__builtin_inff(); lsum[r] = 0.f; }

  const float scale = 0.08838834764831845f;  // 1/sqrt(128)

  if (mysteps > 0) stage(grp, 0);
  __syncthreads();

  for (int i = 0; i < maxst; ++i) {
    if (i + 1 < mysteps) stage(2 * (i + 1) + grp, (i + 1) & 1);
    if (i < mysteps) {
      const int t = 2 * i + grp;
      const int buf = grp * 2 + (i & 1);
      const int kv0 = t * 64;

      f32x4 sc[4];
#pragma unroll
      for (int nf = 0; nf < 4; ++nf) sc[nf] = {};
      __builtin_amdgcn_s_setprio(1);
#pragma unroll
      for (int kk = 0; kk < 4; ++kk) {
#pragma unroll
        for (int nf = 0; nf < 4; ++nf) {
          int row = nf * 16 + l15;
          int dlin = (kk * 32 + lh * 8) ^ ((row & 7) << 3);
          bf16x8 kb = *(const bf16x8*)&kls[buf][row * 128 + dlin];
          sc[nf] = __builtin_amdgcn_mfma_f32_16x16x32_bf16(qa[kk], kb, sc[nf], 0, 0, 0);
        }
      }
      __builtin_amdgcn_s_setprio(0);

      const bool diag = (t == qt);
      const int qg0 = qbase + w4 * 16 + lh * 4;
#pragma unroll
      for (int nf = 0; nf < 4; ++nf) {
        int kvg = kv0 + nf * 16 + l15;
#pragma unroll
        for (int r = 0; r < 4; ++r) {
          float v = sc[nf][r] * scale;
          if (diag && kvg > qg0 + r) v = -__builtin_inff();
          sc[nf][r] = v;
        }
      }

      float mnew[4], alpha[4], rs[4];
#pragma unroll
      for (int r = 0; r < 4; ++r) {
        float v = fmaxf(fmaxf(sc[0][r], sc[1][r]), fmaxf(sc[2][r], sc[3][r]));
#pragma unroll
        for (int sh = 1; sh < 16; sh <<= 1) v = fmaxf(v, __shfl_xor(v, sh));
        mnew[r] = fmaxf(m[r], v);
        alpha[r] = __expf(m[r] - mnew[r]);
        m[r] = mnew[r];
        rs[r] = 0.f;
      }

      bf16* pw = &pld[wave * 16 * 72];
#pragma unroll
      for (int nf = 0; nf < 4; ++nf)
#pragma unroll
        for (int r = 0; r < 4; ++r) {
          float p = __expf(sc[nf][r] - mnew[r]);
          bf16 pb = (bf16)p;
          pw[(lh * 4 + r) * 72 + nf * 16 + l15] = pb;
          rs[r] += (float)pb;
        }
#pragma unroll
      for (int r = 0; r < 4; ++r) {
        float v = rs[r];
#pragma unroll
        for (int sh = 1; sh < 16; sh <<= 1) v += __shfl_xor(v, sh);
        lsum[r] = lsum[r] * alpha[r] + v;
      }
#pragma unroll
      for (int i2 = 0; i2 < 8; ++i2)
#pragma unroll
        for (int r = 0; r < 4; ++r) o[i2][r] *= alpha[r];

      __builtin_amdgcn_s_setprio(1);
#pragma unroll
      for (int kkv = 0; kkv < 2; ++kkv) {
        bf16x8 pa = *(const bf16x8*)&pw[l15 * 72 + kkv * 32 + lh * 8];
#pragma unroll
        for (int df = 0; df < 8; ++df) {
          int dv = df * 16 + l15;
          int klin = (kkv * 32 + lh * 8) ^ ((dv & 7) << 3);
          bf16x8 vb = *(const bf16x8*)&vls[buf][dv * 64 + klin];
          o[df] = __builtin_amdgcn_mfma_f32_16x16x32_bf16(pa, vb, o[df], 0, 0, 0);
        }
      }
      __builtin_amdgcn_s_setprio(0);
    }
    __syncthreads();
  }

  // merge: group1 publishes (o, m, l); group0 combines and stores.
  if (grp == 1) {
#pragma unroll
    for (int df = 0; df < 8; ++df)
#pragma unroll
      for (int r = 0; r < 4; ++r)
        oml[(w4 * 16 + lh * 4 + r) * 128 + df * 16 + l15] = o[df][r];
    if (l15 == 0) {
#pragma unroll
      for (int r = 0; r < 4; ++r) {
        mls[w4 * 16 + lh * 4 + r] = m[r];
        lls[w4 * 16 + lh * 4 + r] = lsum[r];
      }
    }
  }
  __syncthreads();
  if (grp == 0) {
#pragma unroll
    for (int r = 0; r < 4; ++r) {
      int row = w4 * 16 + lh * 4 + r;
      float m1 = mls[row], l1 = lls[row];
      float mm = fmaxf(m[r], m1);
      float s0 = __expf(m[r] - mm);
      float s1 = __expf(m1 - mm);
      float inv = 1.0f / (lsum[r] * s0 + l1 * s1);
      float* op = out + (size_t)(batch * S_LEN + qbase + row) * HD;
#pragma unroll
      for (int df = 0; df < 8; ++df)
        op[df * 16 + l15] =
            (o[df][r] * s0 + oml[row * 128 + df * 16 + l15] * s1) * inv;
    }
  }
}

extern "C" void kernel_launch(void* const* d_in, const int* in_sizes, int n_in,
                              void* d_out, int out_size, void* d_ws, size_t ws_size,
                              hipStream_t stream) {
  const float* x = (const float*)d_in[0];
  const float* Wq = (const float*)d_in[1];
  const float* bq = (const float*)d_in[2];
  const float* Wk = (const float*)d_in[3];
  const float* bk = (const float*)d_in[4];
  const float* Wv = (const float*)d_in[5];
  const float* bv = (const float*)d_in[6];
  float* out = (float*)d_out;

  char* ws = (char*)d_ws;
  bf16* wt  = (bf16*)(ws);                       // 1.5 MB  (Wt, swizzled)
  bf16* Qw  = (bf16*)(ws + (size_t)(2u << 20));  // 4 MB
  bf16* Kw  = (bf16*)(ws + (size_t)(6u << 20));  // 4 MB
  bf16* Vtw = (bf16*)(ws + (size_t)(10u << 20)); // 4 MB

  hipLaunchKernelGGL(k_prep, dim3(192), dim3(256), 0, stream, Wq, Wk, Wv, wt);
  hipLaunchKernelGGL(k_qkv, dim3(512), dim3(512), 0, stream, x, wt, bq, bk, bv,
                     Qw, Kw, Vtw);
  hipLaunchKernelGGL(k_attn, dim3(256), dim3(512), 0, stream, Qw, Kw, Vtw, out);
}

// Round 14
// 97.829 us; speedup vs baseline: 1.1802x; 1.0038x over previous
//
#include <hip/hip_runtime.h>

typedef __bf16 bf16;
typedef __bf16 bf16x8 __attribute__((ext_vector_type(8)));
typedef float f32x4 __attribute__((ext_vector_type(4)));

#define S_LEN 2048
#define EMBD 2048
#define HD 128

__device__ inline void gload16(const void* g, void* l) {
  __builtin_amdgcn_global_load_lds(
      (const __attribute__((address_space(1))) unsigned int*)g,
      (__attribute__((address_space(3))) unsigned int*)l, 16, 0, 0);
}

// ---------------------------------------------------------------------------
// K0: Wt[mat][n][k] = bf16( W[ (k&~63) | ((k&63) ^ ((n&7)<<3)) ][n] )
// Coalesced via LDS transpose: block = (mat, n-tile of 64, k-tile of 64).
// ---------------------------------------------------------------------------
__global__ __launch_bounds__(256) void k_prep(const float* __restrict__ Wq,
                                              const float* __restrict__ Wk,
                                              const float* __restrict__ Wv,
                                              bf16* __restrict__ wt) {
  __shared__ bf16 wls[64 * 72];  // [k][n] padded

  const int t = threadIdx.x;
  const int bid = blockIdx.x;           // 3 * 2 * 32 = 192 blocks
  const int mat = bid >> 6;
  const int nt = bid & 1;
  const int kt = (bid & 63) >> 1;
  const int k0 = kt * 64, n0 = nt * 64;
  const float* W = (mat == 0) ? Wq : ((mat == 1) ? Wk : Wv);

#pragma unroll
  for (int i = 0; i < 4; ++i) {
    int e = i * 256 + t;          // 0..1023
    int r = e >> 4, c4 = e & 15;  // row k, 4-col group
    float4 v = *(const float4*)(W + (size_t)(k0 + r) * HD + n0 + c4 * 4);
    union { bf16 h[4]; uint2 u; } p;
    p.h[0] = (bf16)v.x; p.h[1] = (bf16)v.y;
    p.h[2] = (bf16)v.z; p.h[3] = (bf16)v.w;
    *(uint2*)&wls[r * 72 + c4 * 4] = p.u;
  }
  __syncthreads();
#pragma unroll
  for (int i = 0; i < 2; ++i) {
    int slot = i * 256 + t;  // 0..511: n_loc = slot>>3, kq = slot&7
    int n_loc = slot >> 3, kq = slot & 7;
    int n = n0 + n_loc;
    int kbase = (kq * 8) ^ ((n & 7) << 3);
    union { bf16 h[8]; uint4 u; } p;
#pragma unroll
    for (int j = 0; j < 8; ++j) p.h[j] = wls[(kbase + j) * 72 + n_loc];
    *(uint4*)&wt[(size_t)(mat * HD + n) * EMBD + k0 + kq * 8] = p.u;
  }
}

// ---------------------------------------------------------------------------
// K1: fused QKV GEMM + bias + RoPE. R13 geometry (best measured: 74.8 us):
// BM=64, BN=192, BK=64; by0 = Q + V[0:64], by1 = K + V[64:128]; 512 thr /
// 8 waves (2m x 4n), wave-tile 32x48; xs XOR-swizzled; LDS 64 KB -> 2/CU.
// NEW (T4): raw s_barrier + counted s_waitcnt vmcnt(2) -- per step only the
// w gloads must retire; the x loads for ks+2 (issued after xwrite) stay in
// flight ACROSS the barrier with ~1 full step of slack. No sched_barrier(0).
// ---------------------------------------------------------------------------
__global__ __launch_bounds__(512, 4) void k_qkv(
    const float* __restrict__ x, const bf16* __restrict__ wt,
    const float* __restrict__ bq, const float* __restrict__ bk,
    const float* __restrict__ bv, bf16* __restrict__ Qw, bf16* __restrict__ Kw,
    bf16* __restrict__ Vtw) {
  __shared__ __align__(16) bf16 xs[2][64 * 64];    // 16 KB, XOR-swizzled
  __shared__ __align__(16) bf16 wts[2][192 * 64];  // 48 KB, swizzle pre-baked

  const int tid = threadIdx.x;
  const int lane = tid & 63;
  const int wave = tid >> 6;
  const int wm = wave >> 2;  // 0..1: 32-row half
  const int wn = wave & 3;   // 0..3: 16-col slice
  const int l15 = lane & 15;
  const int lh = lane >> 4;  // 0..3

  const int bid = blockIdx.x;
  const int g = bid >> 3;
  const int by = g & 1;  // 0: Q+Vlo, 1: K+Vhi
  const int mt = (bid & 7) * 32 + (g >> 1);
  const int row0 = mt * 64;

  f32x4 acc[2][3];  // [mf][f]: f0 = col wn*16, f1 = +64 (rope pair), f2 = V
#pragma unroll
  for (int mf = 0; mf < 2; ++mf)
#pragma unroll
    for (int f = 0; f < 3; ++f) acc[mf][f] = {};

  // x staging: 64x64 f32 = 2 float4/thread, coalesced
  int xr_[2], xk_[2];
  const float* xp_[2];
#pragma unroll
  for (int i = 0; i < 2; ++i) {
    int e = (i * 512 + tid) * 4;
    xr_[i] = e >> 6;
    xk_[i] = e & 63;
    xp_[i] = x + (size_t)(row0 + xr_[i]) * EMBD + xk_[i];
  }
  // B staging: 192x64 bf16 = 3 gload16/thread
  const bf16* wp_[3];
  int we_[3];
#pragma unroll
  for (int i = 0; i < 3; ++i) {
    int e = (i * 512 + tid) * 8;
    int np = e >> 6, k = e & 63;  // lds row 0..191
    int ng = (np < 128) ? by * 128 + np : 256 + by * 64 + (np - 128);
    wp_[i] = wt + (size_t)ng * EMBD + k;
    we_[i] = e;
  }

  auto wissue = [&](int ks, int buf) {
#pragma unroll
    for (int i = 0; i < 3; ++i) gload16(wp_[i] + ks * 64, &wts[buf][we_[i]]);
  };
  auto xload = [&](int ks, float4* xr) {
#pragma unroll
    for (int i = 0; i < 2; ++i) xr[i] = *(const float4*)(xp_[i] + ks * 64);
  };
  auto xwrite = [&](int buf, const float4* xr) {
#pragma unroll
    for (int i = 0; i < 2; ++i) {
      union { bf16 h[4]; uint2 u; } p;
      p.h[0] = (bf16)xr[i].x; p.h[1] = (bf16)xr[i].y;
      p.h[2] = (bf16)xr[i].z; p.h[3] = (bf16)xr[i].w;
      // XOR-swizzle (bits 3..5 of elem idx); xk_ is 4-aligned, XOR bits >= 8
      *(uint2*)&xs[buf][xr_[i] * 64 + (xk_[i] ^ ((xr_[i] & 7) << 3))] = p.u;
    }
  };

  float4 xr[2];
  // ---- prologue: w(0)->wts[0]; x(0)->xs[0]; x(1) left in flight in regs ----
  wissue(0, 0);
  xload(0, xr);
  xwrite(0, xr);  // reg-dep wait drains x(0) only
  xload(1, xr);
  asm volatile("s_waitcnt vmcnt(2) lgkmcnt(0)" ::: "memory");  // w(0) landed
  __builtin_amdgcn_s_barrier();

  for (int ks = 0; ks < 32; ++ks) {
    const int c = ks & 1, pbuf = c ^ 1;
    if (ks + 1 < 32) wissue(ks + 1, pbuf);  // oldest of this step's issues

    __builtin_amdgcn_s_setprio(1);
#pragma unroll
    for (int kk = 0; kk < 2; ++kk) {
      bf16x8 a[2];
#pragma unroll
      for (int mf = 0; mf < 2; ++mf) {
        int row = wm * 32 + mf * 16 + l15;
        a[mf] = *(const bf16x8*)&xs[c][row * 64 + ((kk * 32 + lh * 8) ^ ((row & 7) << 3))];
      }
#pragma unroll
      for (int f = 0; f < 3; ++f) {
        int col = (f < 2) ? (f * 64 + wn * 16 + l15) : (128 + wn * 16 + l15);
        int klin = (kk * 32 + lh * 8) ^ ((col & 7) << 3);
        bf16x8 b = *(const bf16x8*)&wts[c][col * 64 + klin];
#pragma unroll
        for (int mf = 0; mf < 2; ++mf)
          acc[mf][f] =
              __builtin_amdgcn_mfma_f32_16x16x32_bf16(a[mf], b, acc[mf][f], 0, 0, 0);
      }
    }
    __builtin_amdgcn_s_setprio(0);

    if (ks + 1 < 32) {
      xwrite(pbuf, xr);              // x(ks+1): regs issued late LAST step
      if (ks + 2 < 32) {
        xload(ks + 2, xr);           // stays in flight across the barrier
        asm volatile("s_waitcnt vmcnt(2) lgkmcnt(0)" ::: "memory");
      } else {
        asm volatile("s_waitcnt vmcnt(0) lgkmcnt(0)" ::: "memory");
      }
      __builtin_amdgcn_s_barrier();
    }
  }
  __syncthreads();  // protect xs reuse in V-epilogue

  const int bb = row0 >> 11;
  const int s0 = row0 & (S_LEN - 1);

  // f0/f1: RoPE pair (Q for by0, K for by1)
  {
    const int colA = wn * 16 + l15;  // 0..63
    const int colB = colA + 64;
    const float* bias = (by == 0) ? bq : bk;
    float biasA = bias[colA], biasB = bias[colB];
    float invf = exp2f((float)colA * -0.20762050593046014f);  // -log2(1e4)/64
#pragma unroll
    for (int mf = 0; mf < 2; ++mf) {
#pragma unroll
      for (int r = 0; r < 4; ++r) {
        int s = s0 + wm * 32 + mf * 16 + lh * 4 + r;
        float xa_ = acc[mf][0][r] + biasA;
        float xb_ = acc[mf][1][r] + biasB;
        float sn, cs;
        sincosf((float)s * invf, &sn, &cs);
        float oa = xa_ * cs - xb_ * sn;
        float ob = xa_ * sn + xb_ * cs;
        if (by == 0) {
          Qw[(size_t)(bb * S_LEN + s) * HD + colA] = (bf16)oa;
          Qw[(size_t)(bb * S_LEN + s) * HD + colB] = (bf16)ob;
        } else {
          int sw = (s & 7) << 3;
          Kw[(size_t)(bb * S_LEN + s) * HD + (colA ^ sw)] = (bf16)oa;
          Kw[(size_t)(bb * S_LEN + s) * HD + (colB ^ sw)] = (bf16)ob;
        }
      }
    }
  }
  // f2: V (no rope) -> LDS transpose stage (xs arena: 64*72 = 4608 elems)
  {
    bf16* vstage = &xs[0][0];
    const int dvl = wn * 16 + l15;  // 0..63 local
    float biasV = bv[by * 64 + dvl];
#pragma unroll
    for (int mf = 0; mf < 2; ++mf)
#pragma unroll
      for (int r = 0; r < 4; ++r) {
        int mrow = wm * 32 + mf * 16 + lh * 4 + r;
        vstage[dvl * 72 + mrow] = (bf16)(acc[mf][2][r] + biasV);
      }
    __syncthreads();
    {  // transposed V store: 512 chunks of 16B, 1 per thread
      int dvl2 = tid >> 3, kq = tid & 7;
      uint4 v = *(const uint4*)&vstage[dvl2 * 72 + kq * 8];
      int dv = by * 64 + dvl2;
      int slot = (kq * 8) ^ ((dvl2 & 7) << 3);
      *(uint4*)&Vtw[((size_t)(bb * HD + dv) << 11) + s0 + slot] = v;
    }
  }
}

// ---------------------------------------------------------------------------
// K2: causal flash attention. 512 thr = 2 groups x 4 waves; groups split the
// KV range (even/odd tiles) and merge (m,l,o) via LDS at the end.
// ---------------------------------------------------------------------------
__global__ __launch_bounds__(512) void k_attn(
    const bf16* __restrict__ Qw, const bf16* __restrict__ Kw,
    const bf16* __restrict__ Vtw, float* __restrict__ out) {
  __shared__ __align__(16) char arena[131072];       // 128 KB: K/V dbuf x 2 grp
  __shared__ __align__(16) bf16 pld[8 * 16 * 72];    // 18.4 KB
  __shared__ float mls[64], lls[64];

  bf16(*kls)[64 * 128] = (bf16(*)[64 * 128])arena;             // [grp*2+buf]
  bf16(*vls)[128 * 64] = (bf16(*)[128 * 64])(arena + 65536);   // [grp*2+buf]
  float* oml = (float*)arena;  // merge area: 64 x 128 f32 (aliases kls[0..1])

  const int tid = threadIdx.x;
  const int lane = tid & 63;
  const int wave = tid >> 6;
  const int grp = wave >> 2;
  const int w4 = wave & 3;
  const int l15 = lane & 15;
  const int lh = lane >> 4;
  const int t256 = tid & 255;

  const int bid = blockIdx.x;
  const int batch = bid & 7;  // batch == XCD (round-robin) -> KV L2 locality
  const int qt = 31 - (bid >> 3);
  const int qbase = qt * 64;
  const int nt = qt + 1;
  const int mysteps = (nt - grp + 1) >> 1;  // grp0: ceil(nt/2), grp1: floor
  const int maxst = (nt + 1) >> 1;

  const bf16* kbat = Kw + (size_t)(batch * S_LEN) * HD;
  const bf16* vbat = Vtw + ((size_t)(batch * HD) << 11);

  auto stage = [&](int t, int buf) {
    bf16* kdst = kls[grp * 2 + buf];
    bf16* vdst = vls[grp * 2 + buf];
    const bf16* kbase = kbat + (size_t)(t * 64) * HD;
#pragma unroll
    for (int i = 0; i < 4; ++i) {
      int c = i * 256 + t256;
      gload16(kbase + c * 8, kdst + c * 8);
    }
    const bf16* vbase = vbat + t * 64;
#pragma unroll
    for (int i = 0; i < 4; ++i) {
      int c = i * 256 + t256;
      int dv = c >> 3, kq = (c & 7) * 8;
      gload16(vbase + ((size_t)dv << 11) + kq, vdst + c * 8);
    }
  };

  bf16x8 qa[4];
  {
    const bf16* qptr = Qw + (size_t)(batch * S_LEN + qbase + w4 * 16 + l15) * HD;
#pragma unroll
    for (int kk = 0; kk < 4; ++kk) qa[kk] = *(const bf16x8*)(qptr + kk * 32 + lh * 8);
  }

  f32x4 o[8];
#pragma unroll
  for (int i = 0; i < 8; ++i) o[i] = {};
  float m[4], lsum[4];
#pragma unroll
  for (int r = 0; r < 4; ++r) { m[r] = -__builtin_inff(); lsum[r] = 0.f; }

  const float scale = 0.08838834764831845f;  // 1/sqrt(128)

  if (mysteps > 0) stage(grp, 0);
  __syncthreads();

  for (int i = 0; i < maxst; ++i) {
    if (i + 1 < mysteps) stage(2 * (i + 1) + grp, (i + 1) & 1);
    if (i < mysteps) {
      const int t = 2 * i + grp;
      const int buf = grp * 2 + (i & 1);
      const int kv0 = t * 64;

      f32x4 sc[4];
#pragma unroll
      for (int nf = 0; nf < 4; ++nf) sc[nf] = {};
      __builtin_amdgcn_s_setprio(1);
#pragma unroll
      for (int kk = 0; kk < 4; ++kk) {
#pragma unroll
        for (int nf = 0; nf < 4; ++nf) {
          int row = nf * 16 + l15;
          int dlin = (kk * 32 + lh * 8) ^ ((row & 7) << 3);
          bf16x8 kb = *(const bf16x8*)&kls[buf][row * 128 + dlin];
          sc[nf] = __builtin_amdgcn_mfma_f32_16x16x32_bf16(qa[kk], kb, sc[nf], 0, 0, 0);
        }
      }
      __builtin_amdgcn_s_setprio(0);

      const bool diag = (t == qt);
      const int qg0 = qbase + w4 * 16 + lh * 4;
#pragma unroll
      for (int nf = 0; nf < 4; ++nf) {
        int kvg = kv0 + nf * 16 + l15;
#pragma unroll
        for (int r = 0; r < 4; ++r) {
          float v = sc[nf][r] * scale;
          if (diag && kvg > qg0 + r) v = -__builtin_inff();
          sc[nf][r] = v;
        }
      }

      float mnew[4], alpha[4], rs[4];
#pragma unroll
      for (int r = 0; r < 4; ++r) {
        float v = fmaxf(fmaxf(sc[0][r], sc[1][r]), fmaxf(sc[2][r], sc[3][r]));
#pragma unroll
        for (int sh = 1; sh < 16; sh <<= 1) v = fmaxf(v, __shfl_xor(v, sh));
        mnew[r] = fmaxf(m[r], v);
        alpha[r] = __expf(m[r] - mnew[r]);
        m[r] = mnew[r];
        rs[r] = 0.f;
      }

      bf16* pw = &pld[wave * 16 * 72];
#pragma unroll
      for (int nf = 0; nf < 4; ++nf)
#pragma unroll
        for (int r = 0; r < 4; ++r) {
          float p = __expf(sc[nf][r] - mnew[r]);
          bf16 pb = (bf16)p;
          pw[(lh * 4 + r) * 72 + nf * 16 + l15] = pb;
          rs[r] += (float)pb;
        }
#pragma unroll
      for (int r = 0; r < 4; ++r) {
        float v = rs[r];
#pragma unroll
        for (int sh = 1; sh < 16; sh <<= 1) v += __shfl_xor(v, sh);
        lsum[r] = lsum[r] * alpha[r] + v;
      }
#pragma unroll
      for (int i2 = 0; i2 < 8; ++i2)
#pragma unroll
        for (int r = 0; r < 4; ++r) o[i2][r] *= alpha[r];

      __builtin_amdgcn_s_setprio(1);
#pragma unroll
      for (int kkv = 0; kkv < 2; ++kkv) {
        bf16x8 pa = *(const bf16x8*)&pw[l15 * 72 + kkv * 32 + lh * 8];
#pragma unroll
        for (int df = 0; df < 8; ++df) {
          int dv = df * 16 + l15;
          int klin = (kkv * 32 + lh * 8) ^ ((dv & 7) << 3);
          bf16x8 vb = *(const bf16x8*)&vls[buf][dv * 64 + klin];
          o[df] = __builtin_amdgcn_mfma_f32_16x16x32_bf16(pa, vb, o[df], 0, 0, 0);
        }
      }
      __builtin_amdgcn_s_setprio(0);
    }
    __syncthreads();
  }

  // merge: group1 publishes (o, m, l); group0 combines and stores.
  if (grp == 1) {
#pragma unroll
    for (int df = 0; df < 8; ++df)
#pragma unroll
      for (int r = 0; r < 4; ++r)
        oml[(w4 * 16 + lh * 4 + r) * 128 + df * 16 + l15] = o[df][r];
    if (l15 == 0) {
#pragma unroll
      for (int r = 0; r < 4; ++r) {
        mls[w4 * 16 + lh * 4 + r] = m[r];
        lls[w4 * 16 + lh * 4 + r] = lsum[r];
      }
    }
  }
  __syncthreads();
  if (grp == 0) {
#pragma unroll
    for (int r = 0; r < 4; ++r) {
      int row = w4 * 16 + lh * 4 + r;
      float m1 = mls[row], l1 = lls[row];
      float mm = fmaxf(m[r], m1);
      float s0 = __expf(m[r] - mm);
      float s1 = __expf(m1 - mm);
      float inv = 1.0f / (lsum[r] * s0 + l1 * s1);
      float* op = out + (size_t)(batch * S_LEN + qbase + row) * HD;
#pragma unroll
      for (int df = 0; df < 8; ++df)
        op[df * 16 + l15] =
            (o[df][r] * s0 + oml[row * 128 + df * 16 + l15] * s1) * inv;
    }
  }
}

extern "C" void kernel_launch(void* const* d_in, const int* in_sizes, int n_in,
                              void* d_out, int out_size, void* d_ws, size_t ws_size,
                              hipStream_t stream) {
  const float* x = (const float*)d_in[0];
  const float* Wq = (const float*)d_in[1];
  const float* bq = (const float*)d_in[2];
  const float* Wk = (const float*)d_in[3];
  const float* bk = (const float*)d_in[4];
  const float* Wv = (const float*)d_in[5];
  const float* bv = (const float*)d_in[6];
  float* out = (float*)d_out;

  char* ws = (char*)d_ws;
  bf16* wt  = (bf16*)(ws);                       // 1.5 MB  (Wt, swizzled)
  bf16* Qw  = (bf16*)(ws + (size_t)(2u << 20));  // 4 MB
  bf16* Kw  = (bf16*)(ws + (size_t)(6u << 20));  // 4 MB
  bf16* Vtw = (bf16*)(ws + (size_t)(10u << 20)); // 4 MB

  hipLaunchKernelGGL(k_prep, dim3(192), dim3(256), 0, stream, Wq, Wk, Wv, wt);
  hipLaunchKernelGGL(k_qkv, dim3(512), dim3(512), 0, stream, x, wt, bq, bk, bv,
                     Qw, Kw, Vtw);
  hipLaunchKernelGGL(k_attn, dim3(256), dim3(512), 0, stream, Qw, Kw, Vtw, out);
}